// Round 10
// baseline (205.105 us; speedup 1.0000x reference)
//
#include <hip/hip_runtime.h>
#include <cfloat>

// ---------------------------------------------------------------------------
// VectorQuantizer: z (16,256,32,32) f32, codebook (8192,256) f32
// outputs (f32 concat): z_q [4194304], loss [1], idx-as-float [16384]
// Validated semantics (R2-R6): idx = argmin_k fl32(zsq - 2*dot32(z,e_k)),
// lowest-index tie-break; bf16-MFMA coarse top-4 x 8 slices -> 32 cands/row;
// prune to coarse margin of row max; survivors re-scored fp64->fp32.
// ARGMIN FROZEN at ~70us (R8/R9/R13/R14 nulls: CU-saturated at 8 waves).
// R15/R16 (169.8us): zq fused into fixup (cand in d_ws), zsq fused into
//   fixup, prep slimmed. argmin at R1's proven form.
// R17: attribution + write-coalescing:
//   - argmin split into 2 dispatches (slices 0-3 / 4-7, 256 blocks each) so
//     fixup/prep (never yet profiled; ~100us unattributed) surface in the
//     rocprof top-5. Sum unchanged.
//   - fused z_q scatter re-mapped: lane=(hw-quad, ch-group) -> 8x128B
//     contiguous segments/instr (was 64x16B at 4KB stride = write
//     amplification on the 16MB z_q write).
// ---------------------------------------------------------------------------

#define NROWS 16384
#define NCODE 8192
#define DIMC  256
#define HW    1024
#define ZQN   4194304

// scratch inside d_out's z_q region (dead before z_q is written):
#define ZT_OFF   0         // bf16 z*2^21 [16384][256] as ushort = 2097152 floats
#define CBT_OFF  2097152   // bf16 codebook [8192][256]          = 1048576 floats
#define CAND_OFF 3145728   // fallback cand: 8*16384*4 uints -> ends 3670016
#define LOSS_OFF ZQN
#define IDX_OFF  (ZQN + 1)

#define NSLICE 8
#define CAND_BYTES ((size_t)NSLICE * NROWS * 4 * sizeof(unsigned))   // 2 MB
#define PRUNE_T 4300u      // key units (8 float-ulps each, worst 1.49e-8 dot):
                           // covers d-bin 3.05e-5 + 2x6sigma bf16 + tag-quant
#define ZSCALE 2097152.0f  // 2^21, exact in bf16/f32

typedef __attribute__((ext_vector_type(8))) short bf16x8;
typedef __attribute__((ext_vector_type(4))) float f32x4;
typedef __attribute__((ext_vector_type(4))) unsigned int uint4v;

__device__ __forceinline__ unsigned umax(unsigned a, unsigned b) { return a > b ? a : b; }
__device__ __forceinline__ unsigned umin(unsigned a, unsigned b) { return a < b ? a : b; }

__device__ __forceinline__ unsigned short f2bf(float f) {   // RNE
    unsigned u = __float_as_uint(f);
    return (unsigned short)((u + 0x7fffu + ((u >> 16) & 1u)) >> 16);
}

#define GLD_LDS16(gptr, lptr) \
  __builtin_amdgcn_global_load_lds((const __attribute__((address_space(1))) unsigned int*)(const void*)(gptr), \
                                   (__attribute__((address_space(3))) unsigned int*)(lptr), 16, 0, 0)

// --- 1: fused prep: zt transpose+cvt(*2^21) | cbt cvt | loss zero ----------
__global__ void prep_kernel(const float* __restrict__ z, const float* __restrict__ cb,
                            float* __restrict__ out) {
    int bid = blockIdx.x;
    int tid = threadIdx.x;
    if (bid < 1024) {
        __shared__ unsigned short lds[64 * 65];
        unsigned short* zt = (unsigned short*)(out + ZT_OFF);
        int c0 = (bid & 3) * 64;
        int n0 = (bid >> 2) * 64;
        const float* zb = z + (size_t)(n0 >> 10) * (DIMC * HW) + (n0 & 1023);
        #pragma unroll
        for (int i = 0; i < 4; ++i) {
            int f = tid + i * 256;
            int cl = f >> 4, n4 = f & 15;
            float4 v = *(const float4*)(zb + (size_t)(c0 + cl) * HW + n4 * 4);
            lds[(n4 * 4 + 0) * 65 + cl] = f2bf(v.x * ZSCALE);
            lds[(n4 * 4 + 1) * 65 + cl] = f2bf(v.y * ZSCALE);
            lds[(n4 * 4 + 2) * 65 + cl] = f2bf(v.z * ZSCALE);
            lds[(n4 * 4 + 3) * 65 + cl] = f2bf(v.w * ZSCALE);
        }
        __syncthreads();
        #pragma unroll
        for (int i = 0; i < 2; ++i) {
            int f = tid + i * 256;
            int nl = f >> 3, oct = f & 7;
            const unsigned short* p = lds + nl * 65 + oct * 8;
            uint4v u;
            u.x = (unsigned)p[0] | ((unsigned)p[1] << 16);
            u.y = (unsigned)p[2] | ((unsigned)p[3] << 16);
            u.z = (unsigned)p[4] | ((unsigned)p[5] << 16);
            u.w = (unsigned)p[6] | ((unsigned)p[7] << 16);
            *(uint4v*)(zt + (size_t)(n0 + nl) * DIMC + c0 + oct * 8) = u;
        }
    } else {
        unsigned short* cbt = (unsigned short*)(out + CBT_OFF);
        size_t t = (size_t)(bid - 1024) * 256 + tid;
        float4 a = *(const float4*)(cb + t * 8);
        float4 b = *(const float4*)(cb + t * 8 + 4);
        uint4v u;
        u.x = (unsigned)f2bf(a.x) | ((unsigned)f2bf(a.y) << 16);
        u.y = (unsigned)f2bf(a.z) | ((unsigned)f2bf(a.w) << 16);
        u.z = (unsigned)f2bf(b.x) | ((unsigned)f2bf(b.y) << 16);
        u.w = (unsigned)f2bf(b.z) | ((unsigned)f2bf(b.w) << 16);
        *(uint4v*)(cbt + t * 8) = u;
        if (bid == 1024 && tid == 0) out[LOSS_OFF] = 0.0f;
    }
}

// --- 2: bf16 MFMA argmin (R1's proven form; slice_base for split dispatch) -
// grid (64 row-blocks, 4 slices) x2 dispatches. Block: 256 rows x 1024 codes.
__global__ __launch_bounds__(256, 2)
void argmin_kernel(const float* __restrict__ out, unsigned* __restrict__ cand,
                   int slice_base) {
    __shared__ __align__(16) unsigned short a_s[2 * 32 * 256];   // 32 KB dbuf
    const unsigned short* zt  = (const unsigned short*)(out + ZT_OFF);
    const unsigned short* cbt = (const unsigned short*)(out + CBT_OFF);

    int tid = threadIdx.x;
    int lane = tid & 63;
    int wv = tid >> 6;
    int col = lane & 15, qk = lane >> 4;
    int n0 = blockIdx.x * 256;
    int slice = blockIdx.y + slice_base;

    bf16x8 B[4][8];
    #pragma unroll
    for (int rf = 0; rf < 4; ++rf)
        #pragma unroll
        for (int t = 0; t < 8; ++t)
            B[rf][t] = *(const bf16x8*)(zt + (size_t)(n0 + wv * 64 + rf * 16 + col) * DIMC
                                           + t * 32 + qk * 8);

    int rl2 = lane >> 5;
    int jsl = lane & 31;
    const unsigned short* srcb[4];
    #pragma unroll
    for (int c = 0; c < 4; ++c) {
        int rloc = (wv * 4 + c) * 2 + rl2;
        int src16 = jsl ^ (rloc & 7) ^ ((rloc & 8) >> 1);
        srcb[c] = cbt + ((size_t)slice * 1024 + rloc) * DIMC + src16 * 8;
    }

    unsigned U1[4] = {0, 0, 0, 0}, U2[4] = {0, 0, 0, 0};

    const unsigned sb = (unsigned)((col & 7) ^ ((col & 8) >> 1));
    const unsigned short* aoff[8];
    #pragma unroll
    for (int t = 0; t < 8; ++t)
        aoff[t] = a_s + col * 256 + (((unsigned)(qk + 4 * t)) ^ sb) * 8;

    f32x4 acc[4][2];
    const f32x4 BIASV = (f32x4){131072.0f, 131072.0f, 131072.0f, 131072.0f};

    auto stage = [&](int ch, int dsto /*shorts*/) {
        const size_t off = (size_t)ch * 32 * DIMC;
        unsigned short* dst = a_s + dsto;
        #pragma unroll
        for (int c = 0; c < 4; ++c)
            GLD_LDS16(srcb[c] + off, dst + (wv * 4 + c) * 512);
    };

    auto epi1 = [&](unsigned tb) {
        #pragma unroll
        for (int rf = 0; rf < 4; ++rf)
            #pragma unroll
            for (int r = 0; r < 4; ++r) {
                unsigned bits = __float_as_uint(acc[rf][1][r]);
                unsigned u = (bits & 0xFFFFFF00u) | (tb - (unsigned)(4 + r));
                unsigned lo = umin(u, U1[rf]);
                U1[rf] = umax(u, U1[rf]);
                U2[rf] = umax(lo, U2[rf]);
            }
    };

    auto compute = [&](int bufb /*bytes*/, unsigned tb) {
        #pragma unroll
        for (int rf = 0; rf < 4; ++rf) acc[rf][0] = BIASV;
        #pragma unroll
        for (int t = 0; t < 8; ++t) {
            bf16x8 af = *(const bf16x8*)((const char*)aoff[t] + bufb);
            acc[0][0] = __builtin_amdgcn_mfma_f32_16x16x32_bf16(af, B[0][t], acc[0][0], 0, 0, 0);
            acc[1][0] = __builtin_amdgcn_mfma_f32_16x16x32_bf16(af, B[1][t], acc[1][0], 0, 0, 0);
            acc[2][0] = __builtin_amdgcn_mfma_f32_16x16x32_bf16(af, B[2][t], acc[2][0], 0, 0, 0);
            acc[3][0] = __builtin_amdgcn_mfma_f32_16x16x32_bf16(af, B[3][t], acc[3][0], 0, 0, 0);
        }
        #pragma unroll
        for (int rf = 0; rf < 4; ++rf) acc[rf][1] = BIASV;
        #pragma unroll
        for (int t = 0; t < 8; ++t) {
            bf16x8 af = *(const bf16x8*)((const char*)aoff[t] + bufb + 8192);
            acc[0][1] = __builtin_amdgcn_mfma_f32_16x16x32_bf16(af, B[0][t], acc[0][1], 0, 0, 0);
            acc[1][1] = __builtin_amdgcn_mfma_f32_16x16x32_bf16(af, B[1][t], acc[1][1], 0, 0, 0);
            acc[2][1] = __builtin_amdgcn_mfma_f32_16x16x32_bf16(af, B[2][t], acc[2][1], 0, 0, 0);
            acc[3][1] = __builtin_amdgcn_mfma_f32_16x16x32_bf16(af, B[3][t], acc[3][1], 0, 0, 0);
            {   // interleave: 2 cf0 scores of THIS chunk per t-step
                const int q0 = 2 * t, q1 = 2 * t + 1;
                const int rfA = q0 >> 2, rA = q0 & 3;
                const int rfB = q1 >> 2, rB = q1 & 3;
                unsigned bitsA = __float_as_uint(acc[rfA][0][rA]);
                unsigned uA = (bitsA & 0xFFFFFF00u) | (tb - (unsigned)rA);
                unsigned loA = umin(uA, U1[rfA]);
                U1[rfA] = umax(uA, U1[rfA]);
                U2[rfA] = umax(loA, U2[rfA]);
                unsigned bitsB = __float_as_uint(acc[rfB][0][rB]);
                unsigned uB = (bitsB & 0xFFFFFF00u) | (tb - (unsigned)rB);
                unsigned loB = umin(uB, U1[rfB]);
                U1[rfB] = umax(uB, U1[rfB]);
                U2[rfB] = umax(loB, U2[rfB]);
            }
        }
    };

    // 32 chunks, double-buffered (R1's proven schedule)
    stage(0, 0);
    __syncthreads();                  // drains B-loads + GLD(0)
    stage(1, 8192);
    compute(0, 255u);                 // chunk 0 (buf0)

    #pragma unroll 1
    for (int k = 0; k < 15; ++k) {
        const int c1 = 2 * k + 1;
        const unsigned tb = 255u - ((unsigned)c1 << 3);
        __syncthreads();
        stage(c1 + 1, 0);             // chunk 2k+2 -> buf0
        epi1(tb + 8u);                // cf1 of chunk 2k
        compute(16384, tb);           // chunk 2k+1 (buf1)
        __syncthreads();
        stage(c1 + 2, 8192);          // chunk 2k+3 -> buf1 (k=14 stages 31)
        epi1(tb);                     // cf1 of chunk 2k+1
        compute(0, tb - 8u);          // chunk 2k+2 (buf0)
    }
    __syncthreads();                  // drains GLD(31)
    epi1(255u - (30u << 3));
    compute(16384, 255u - (31u << 3));
    epi1(255u - (31u << 3));

    // decode to (key22<<10 | 1023-local), cross-qk merge top-4, store packed
    #pragma unroll
    for (int rf = 0; rf < 4; ++rf) {
        unsigned t1 = 255u - (U1[rf] & 255u);
        unsigned c1 = (t1 >> 3) * 32 + ((t1 >> 2) & 1) * 16 + qk * 4 + (t1 & 3);
        unsigned x1 = ((((U1[rf] & 0xFFFFFF00u) - 0x47000000u) >> 3) << 10) | (1023u - c1);
        unsigned t2 = 255u - (U2[rf] & 255u);
        unsigned c2 = (t2 >> 3) * 32 + ((t2 >> 2) & 1) * 16 + qk * 4 + (t2 & 3);
        unsigned x2 = ((((U2[rf] & 0xFFFFFF00u) - 0x47000000u) >> 3) << 10) | (1023u - c2);
        unsigned p1 = __shfl_xor(x1, 16);
        unsigned p2 = __shfl_xor(x2, 16);
        unsigned s1 = umax(x1, p1), tm = umin(x1, p1);
        unsigned ym = umax(x2, p2), s4 = umin(x2, p2);
        unsigned s2 = umax(tm, ym), s3 = umin(tm, ym);
        unsigned r1 = umax(s1, __shfl_xor(s4, 32));
        unsigned r2 = umax(s2, __shfl_xor(s3, 32));
        unsigned r3 = umax(s3, __shfl_xor(s2, 32));
        unsigned r4 = umax(s4, __shfl_xor(s1, 32));
        if (qk == 0) {
            int row = wv * 64 + rf * 16 + col;
            uint4v cw; cw.x = r1; cw.y = r2; cw.z = r3; cw.w = r4;
            *(uint4v*)(cand + ((size_t)slice * NROWS + n0 + row) * 4) = cw;
        }
    }
}

// --- 3: prune + in-block zsq + fp64 re-score + loss [+ fused z_q write] ----
// 512 blocks x 256 threads; block = 32 rows x 32 candidates.
__global__ __launch_bounds__(256, 2)
void fixup_kernel(const float* __restrict__ z, const float* __restrict__ cb,
                  float* __restrict__ out, const unsigned* __restrict__ cand,
                  int fuse_zq) {
    __shared__ float zs[32 * 264];       // [row][c^((row>>2)<<2)], pad 8
    __shared__ double dp[8][32];         // zsq partials
    __shared__ float zsq_s[32];
    __shared__ unsigned qmx[32];
    __shared__ float dsc[32 * 33];       // [row][j]
    __shared__ unsigned cds[32 * 33];
    __shared__ unsigned bcode[32];
    __shared__ double lred[4];
    int tid = threadIdx.x;
    int n0 = blockIdx.x * 32;
    const float* zb = z + (size_t)(n0 >> 10) * (DIMC * HW) + (n0 & 1023);

    // stage z tile: thread = (row-quad q, channel cq); 128B segments
    {
        int q = tid & 7, cq = tid >> 3;
        #pragma unroll
        for (int i = 0; i < 8; ++i) {
            int c = cq + i * 32;
            float4 v = *(const float4*)(zb + (size_t)c * HW + q * 4);
            int sc = c ^ (q << 2);
            zs[(q * 4 + 0) * 264 + sc] = v.x;
            zs[(q * 4 + 1) * 264 + sc] = v.y;
            zs[(q * 4 + 2) * 264 + sc] = v.z;
            zs[(q * 4 + 3) * 264 + sc] = v.w;
        }
    }
    if (tid < 32) qmx[tid] = 0;

    // candidate words for all 4 row-batches (coalesced 128B segments)
    int j = tid >> 3, r = tid & 7;
    unsigned w[4];
    #pragma unroll
    for (int b = 0; b < 4; ++b)
        w[b] = cand[(((size_t)(j >> 2)) * NROWS + n0 + b * 8 + r) * 4 + (j & 3)];
    __syncthreads();

    // zsq from staged tile (f64, fixed order) + coarse row-max
    {
        int row = tid & 31, cg = tid >> 5;
        const float* zrow = zs + row * 264;
        const int xr = (row >> 2) << 2;
        double s = 0.0;
        #pragma unroll
        for (int i = 0; i < 8; ++i) {
            int c = cg * 32 + i * 4;
            float4 zv = *(const float4*)(zrow + (c ^ xr));
            s += (double)zv.x * (double)zv.x + (double)zv.y * (double)zv.y
               + (double)zv.z * (double)zv.z + (double)zv.w * (double)zv.w;
        }
        dp[cg][row] = s;
    }
    #pragma unroll
    for (int b = 0; b < 4; ++b)
        atomicMax(&qmx[b * 8 + r], w[b] >> 10);
    __syncthreads();
    if (tid < 32) {
        double s = ((dp[0][tid] + dp[1][tid]) + (dp[2][tid] + dp[3][tid]))
                 + ((dp[4][tid] + dp[5][tid]) + (dp[6][tid] + dp[7][tid]));
        zsq_s[tid] = (float)s;
    }
    __syncthreads();

    // 4 batches of the validated 8-row x 32-cand fp64 re-score
    #pragma unroll 1
    for (int b = 0; b < 4; ++b) {
        int row = b * 8 + r;
        unsigned qv = w[b] >> 10;
        unsigned code = (unsigned)((j >> 2) * 1024) + 1023u - (w[b] & 1023u);
        bool live = (qv + PRUNE_T >= qmx[row]);
        float d = FLT_MAX;
        if (live) {
            const float* e = cb + (size_t)code * DIMC;
            const float* zrow = zs + row * 264;
            const int xr = (row >> 2) << 2;
            double a0 = 0.0, a1 = 0.0, a2 = 0.0, a3 = 0.0;
            for (int c = 0; c < DIMC; c += 16) {
                float4 e0 = *(const float4*)(e + c);
                float4 e1 = *(const float4*)(e + c + 4);
                float4 e2 = *(const float4*)(e + c + 8);
                float4 e3 = *(const float4*)(e + c + 12);
                float4 z0 = *(const float4*)(zrow + ((c) ^ xr));
                float4 z1 = *(const float4*)(zrow + ((c + 4) ^ xr));
                float4 z2 = *(const float4*)(zrow + ((c + 8) ^ xr));
                float4 z3 = *(const float4*)(zrow + ((c + 12) ^ xr));
                a0 += (double)z0.x * (double)e0.x + (double)z0.y * (double)e0.y
                    + (double)z0.z * (double)e0.z + (double)z0.w * (double)e0.w;
                a1 += (double)z1.x * (double)e1.x + (double)z1.y * (double)e1.y
                    + (double)z1.z * (double)e1.z + (double)z1.w * (double)e1.w;
                a2 += (double)z2.x * (double)e2.x + (double)z2.y * (double)e2.y
                    + (double)z2.z * (double)e2.z + (double)z2.w * (double)e2.w;
                a3 += (double)z3.x * (double)e3.x + (double)z3.y * (double)e3.y
                    + (double)z3.z * (double)e3.z + (double)z3.w * (double)e3.w;
            }
            d = fmaf(-2.0f, (float)((a0 + a1) + (a2 + a3)), zsq_s[row]);
        }
        dsc[row * 33 + j] = d;
        cds[row * 33 + j] = code;
    }
    __syncthreads();
    if (tid < 32) {
        float bd = FLT_MAX; unsigned bi = 0xffffffffu;
        for (int jj = 0; jj < 32; ++jj) {
            float dv = dsc[tid * 33 + jj];
            unsigned k = cds[tid * 33 + jj];
            if (dv < bd || (dv == bd && k < bi)) { bd = dv; bi = k; }
        }
        out[IDX_OFF + n0 + tid] = (float)bi;
        bcode[tid] = bi;
    }
    __syncthreads();

    // fused loss on the staged tile: thread = (row, c-32-group), f64 partial
    {
        int row = tid & 31, cg = tid >> 5;
        const float* zrow = zs + row * 264;
        const int xr = (row >> 2) << 2;
        const float* e = cb + (size_t)bcode[row] * DIMC;
        double lacc = 0.0;
        #pragma unroll
        for (int i = 0; i < 8; ++i) {
            int c = cg * 32 + (((i + row) & 7) << 2);   // staggered quads
            float4 ev = *(const float4*)(e + c);
            float4 zv = *(const float4*)(zrow + (c ^ xr));
            double d0 = (double)ev.x - (double)zv.x;
            double d1 = (double)ev.y - (double)zv.y;
            double d2 = (double)ev.z - (double)zv.z;
            double d3 = (double)ev.w - (double)zv.w;
            lacc += d0 * d0 + d1 * d1 + d2 * d2 + d3 * d3;
        }
        #pragma unroll
        for (int off = 32; off; off >>= 1) lacc += __shfl_down(lacc, off);
        if ((tid & 63) == 0) lred[tid >> 6] = lacc;
    }
    __syncthreads();                 // all zs reads complete past this point
    if (tid == 0) {
        double part = (lred[0] + lred[1]) + (lred[2] + lred[3]);
        atomicAdd(out + LOSS_OFF, (float)(part * (1.25 / 4194304.0)));
    }

    if (fuse_zq) {
        // gather winner rows into zs (unswizzled [row][264])
        {
            int rr = tid >> 3, q = tid & 7;
            const float* e = cb + (size_t)bcode[rr] * DIMC;
            #pragma unroll
            for (int i = 0; i < 8; ++i) {
                int c = i * 32 + q * 4;
                *(float4*)(zs + rr * 264 + c) = *(const float4*)(e + c);
            }
        }
        __syncthreads();
        // scatter z_q: lane = (hw-quad 0-7, ch-group 0-31) -> per instr,
        // 8 lanes cover 8 consecutive 16B quads of one channel = 128B segs
        int hwq = tid & 7, ch0 = tid >> 3;
        int bb = n0 >> 10, hw0 = n0 & 1023;
        float* zqbase = out + (size_t)bb * (DIMC * HW) + hw0 + hwq * 4;
        #pragma unroll
        for (int i = 0; i < 8; ++i) {
            int c = ch0 + i * 32;
            float4 v;
            v.x = zs[(hwq * 4 + 0) * 264 + c];
            v.y = zs[(hwq * 4 + 1) * 264 + c];
            v.z = zs[(hwq * 4 + 2) * 264 + c];
            v.w = zs[(hwq * 4 + 3) * 264 + c];
            *(float4*)(zqbase + (size_t)c * HW) = v;
        }
    }
}

// --- 4 (fallback only): z_q gather->scatter, 1024 blocks x 256 thr ---------
__global__ __launch_bounds__(256)
void zq_kernel(const float* __restrict__ z, const float* __restrict__ cb,
               float* __restrict__ out) {
    __shared__ float lds[16 * 260];
    int tid = threadIdx.x;
    int n0 = blockIdx.x * 16;
    {
        int rr = tid >> 4, q = tid & 15;
        int code = (int)out[IDX_OFF + n0 + rr];
        const float* e = cb + (size_t)code * DIMC;
        #pragma unroll
        for (int jj = 0; jj < 4; ++jj) {
            int c = q * 4 + jj * 64;
            *(float4*)(lds + rr * 260 + c) = *(const float4*)(e + c);
        }
    }
    __syncthreads();
    int g = tid >> 2, rq = tid & 3;
    int b = n0 >> 10, hw0 = n0 & 1023;
    const size_t base = (size_t)b * (DIMC * HW) + hw0 + rq * 4;
    #pragma unroll
    for (int i = 0; i < 4; ++i) {
        int c = g + i * 64;
        float4 v;
        v.x = lds[(rq * 4 + 0) * 260 + c];
        v.y = lds[(rq * 4 + 1) * 260 + c];
        v.z = lds[(rq * 4 + 2) * 260 + c];
        v.w = lds[(rq * 4 + 3) * 260 + c];
        *(float4*)(out + base + (size_t)c * HW) = v;
    }
}

extern "C" void kernel_launch(void* const* d_in, const int* in_sizes, int n_in,
                              void* d_out, int out_size, void* d_ws, size_t ws_size,
                              hipStream_t stream) {
    const float* z  = (const float*)d_in[0];
    const float* cb = (const float*)d_in[1];
    float* out = (float*)d_out;

    const bool fuse = (d_ws != nullptr) && (ws_size >= CAND_BYTES);
    unsigned* candp = fuse ? (unsigned*)d_ws : (unsigned*)(out + CAND_OFF);

    prep_kernel<<<2048, 256, 0, stream>>>(z, cb, out);
    argmin_kernel<<<dim3(64, NSLICE / 2), 256, 0, stream>>>(out, candp, 0);
    argmin_kernel<<<dim3(64, NSLICE / 2), 256, 0, stream>>>(out, candp, 4);
    fixup_kernel<<<512, 256, 0, stream>>>(z, cb, out, candp, fuse ? 1 : 0);
    if (!fuse)
        zq_kernel<<<1024, 256, 0, stream>>>(z, cb, out);
}

// Round 11
// 156.545 us; speedup vs baseline: 1.3102x; 1.3102x over previous
//
#include <hip/hip_runtime.h>
#include <cfloat>

// ---------------------------------------------------------------------------
// VectorQuantizer: z (16,256,32,32) f32, codebook (8192,256) f32
// outputs (f32 concat): z_q [4194304], loss [1], idx-as-float [16384]
// Validated semantics (R2-R6): idx = argmin_k fl32(zsq - 2*dot32(z,e_k)),
// lowest-index tie-break; bf16-MFMA coarse top-4 x 8 slices -> 32 cands/row;
// prune to coarse margin of row max; survivors re-scored fp64->fp32.
// ARGMIN FROZEN at ~70us, 8 waves/CU saturation (R8/R9/R13/R14 nulls;
//   R17's 1-block/CU split regressed -> reverted to single dispatch).
// R17 attribution: fixup = 48.8us, latency-bound (VALU 26%, HBM 11%,
//   occ 16%) — serial per-thread 256-dim f64 dots with masked-lane waste
//   and unoverlapped cb gathers.
// R18: fixup v3: live candidates compacted into an LDS worklist, then
//   8-lane cooperative dots (lane l: dims k*32+l*4 -> per-k contiguous 128B
//   cb reads; z-LDS banks distinct across lanes; 3-step shfl_xor f64
//   reduce). Removes masked-wave cost, 8x dot parallelism, pipelined
//   gathers. Keeps R17's coalesced fused z_q scatter.
// ---------------------------------------------------------------------------

#define NROWS 16384
#define NCODE 8192
#define DIMC  256
#define HW    1024
#define ZQN   4194304

// scratch inside d_out's z_q region (dead before z_q is written):
#define ZT_OFF   0         // bf16 z*2^21 [16384][256] as ushort = 2097152 floats
#define CBT_OFF  2097152   // bf16 codebook [8192][256]          = 1048576 floats
#define CAND_OFF 3145728   // fallback cand: 8*16384*4 uints -> ends 3670016
#define LOSS_OFF ZQN
#define IDX_OFF  (ZQN + 1)

#define NSLICE 8
#define CAND_BYTES ((size_t)NSLICE * NROWS * 4 * sizeof(unsigned))   // 2 MB
#define PRUNE_T 4300u      // key units (8 float-ulps each, worst 1.49e-8 dot):
                           // covers d-bin 3.05e-5 + 2x6sigma bf16 + tag-quant
#define ZSCALE 2097152.0f  // 2^21, exact in bf16/f32

typedef __attribute__((ext_vector_type(8))) short bf16x8;
typedef __attribute__((ext_vector_type(4))) float f32x4;
typedef __attribute__((ext_vector_type(4))) unsigned int uint4v;

__device__ __forceinline__ unsigned umax(unsigned a, unsigned b) { return a > b ? a : b; }
__device__ __forceinline__ unsigned umin(unsigned a, unsigned b) { return a < b ? a : b; }

__device__ __forceinline__ unsigned short f2bf(float f) {   // RNE
    unsigned u = __float_as_uint(f);
    return (unsigned short)((u + 0x7fffu + ((u >> 16) & 1u)) >> 16);
}

#define GLD_LDS16(gptr, lptr) \
  __builtin_amdgcn_global_load_lds((const __attribute__((address_space(1))) unsigned int*)(const void*)(gptr), \
                                   (__attribute__((address_space(3))) unsigned int*)(lptr), 16, 0, 0)

// --- 1: fused prep: zt transpose+cvt(*2^21) | cbt cvt | loss zero ----------
__global__ void prep_kernel(const float* __restrict__ z, const float* __restrict__ cb,
                            float* __restrict__ out) {
    int bid = blockIdx.x;
    int tid = threadIdx.x;
    if (bid < 1024) {
        __shared__ unsigned short lds[64 * 65];
        unsigned short* zt = (unsigned short*)(out + ZT_OFF);
        int c0 = (bid & 3) * 64;
        int n0 = (bid >> 2) * 64;
        const float* zb = z + (size_t)(n0 >> 10) * (DIMC * HW) + (n0 & 1023);
        #pragma unroll
        for (int i = 0; i < 4; ++i) {
            int f = tid + i * 256;
            int cl = f >> 4, n4 = f & 15;
            float4 v = *(const float4*)(zb + (size_t)(c0 + cl) * HW + n4 * 4);
            lds[(n4 * 4 + 0) * 65 + cl] = f2bf(v.x * ZSCALE);
            lds[(n4 * 4 + 1) * 65 + cl] = f2bf(v.y * ZSCALE);
            lds[(n4 * 4 + 2) * 65 + cl] = f2bf(v.z * ZSCALE);
            lds[(n4 * 4 + 3) * 65 + cl] = f2bf(v.w * ZSCALE);
        }
        __syncthreads();
        #pragma unroll
        for (int i = 0; i < 2; ++i) {
            int f = tid + i * 256;
            int nl = f >> 3, oct = f & 7;
            const unsigned short* p = lds + nl * 65 + oct * 8;
            uint4v u;
            u.x = (unsigned)p[0] | ((unsigned)p[1] << 16);
            u.y = (unsigned)p[2] | ((unsigned)p[3] << 16);
            u.z = (unsigned)p[4] | ((unsigned)p[5] << 16);
            u.w = (unsigned)p[6] | ((unsigned)p[7] << 16);
            *(uint4v*)(zt + (size_t)(n0 + nl) * DIMC + c0 + oct * 8) = u;
        }
    } else {
        unsigned short* cbt = (unsigned short*)(out + CBT_OFF);
        size_t t = (size_t)(bid - 1024) * 256 + tid;
        float4 a = *(const float4*)(cb + t * 8);
        float4 b = *(const float4*)(cb + t * 8 + 4);
        uint4v u;
        u.x = (unsigned)f2bf(a.x) | ((unsigned)f2bf(a.y) << 16);
        u.y = (unsigned)f2bf(a.z) | ((unsigned)f2bf(a.w) << 16);
        u.z = (unsigned)f2bf(b.x) | ((unsigned)f2bf(b.y) << 16);
        u.w = (unsigned)f2bf(b.z) | ((unsigned)f2bf(b.w) << 16);
        *(uint4v*)(cbt + t * 8) = u;
        if (bid == 1024 && tid == 0) out[LOSS_OFF] = 0.0f;
    }
}

// --- 2: bf16 MFMA argmin (R1's proven 69.5us form) -------------------------
// grid (64 row-blocks, 8 slices), 256 threads. Block: 256 rows x 1024 codes.
__global__ __launch_bounds__(256, 2)
void argmin_kernel(const float* __restrict__ out, unsigned* __restrict__ cand) {
    __shared__ __align__(16) unsigned short a_s[2 * 32 * 256];   // 32 KB dbuf
    const unsigned short* zt  = (const unsigned short*)(out + ZT_OFF);
    const unsigned short* cbt = (const unsigned short*)(out + CBT_OFF);

    int tid = threadIdx.x;
    int lane = tid & 63;
    int wv = tid >> 6;
    int col = lane & 15, qk = lane >> 4;
    int n0 = blockIdx.x * 256;
    int slice = blockIdx.y;

    bf16x8 B[4][8];
    #pragma unroll
    for (int rf = 0; rf < 4; ++rf)
        #pragma unroll
        for (int t = 0; t < 8; ++t)
            B[rf][t] = *(const bf16x8*)(zt + (size_t)(n0 + wv * 64 + rf * 16 + col) * DIMC
                                           + t * 32 + qk * 8);

    int rl2 = lane >> 5;
    int jsl = lane & 31;
    const unsigned short* srcb[4];
    #pragma unroll
    for (int c = 0; c < 4; ++c) {
        int rloc = (wv * 4 + c) * 2 + rl2;
        int src16 = jsl ^ (rloc & 7) ^ ((rloc & 8) >> 1);
        srcb[c] = cbt + ((size_t)slice * 1024 + rloc) * DIMC + src16 * 8;
    }

    unsigned U1[4] = {0, 0, 0, 0}, U2[4] = {0, 0, 0, 0};

    const unsigned sb = (unsigned)((col & 7) ^ ((col & 8) >> 1));
    const unsigned short* aoff[8];
    #pragma unroll
    for (int t = 0; t < 8; ++t)
        aoff[t] = a_s + col * 256 + (((unsigned)(qk + 4 * t)) ^ sb) * 8;

    f32x4 acc[4][2];
    const f32x4 BIASV = (f32x4){131072.0f, 131072.0f, 131072.0f, 131072.0f};

    auto stage = [&](int ch, int dsto /*shorts*/) {
        const size_t off = (size_t)ch * 32 * DIMC;
        unsigned short* dst = a_s + dsto;
        #pragma unroll
        for (int c = 0; c < 4; ++c)
            GLD_LDS16(srcb[c] + off, dst + (wv * 4 + c) * 512);
    };

    auto epi1 = [&](unsigned tb) {
        #pragma unroll
        for (int rf = 0; rf < 4; ++rf)
            #pragma unroll
            for (int r = 0; r < 4; ++r) {
                unsigned bits = __float_as_uint(acc[rf][1][r]);
                unsigned u = (bits & 0xFFFFFF00u) | (tb - (unsigned)(4 + r));
                unsigned lo = umin(u, U1[rf]);
                U1[rf] = umax(u, U1[rf]);
                U2[rf] = umax(lo, U2[rf]);
            }
    };

    auto compute = [&](int bufb /*bytes*/, unsigned tb) {
        #pragma unroll
        for (int rf = 0; rf < 4; ++rf) acc[rf][0] = BIASV;
        #pragma unroll
        for (int t = 0; t < 8; ++t) {
            bf16x8 af = *(const bf16x8*)((const char*)aoff[t] + bufb);
            acc[0][0] = __builtin_amdgcn_mfma_f32_16x16x32_bf16(af, B[0][t], acc[0][0], 0, 0, 0);
            acc[1][0] = __builtin_amdgcn_mfma_f32_16x16x32_bf16(af, B[1][t], acc[1][0], 0, 0, 0);
            acc[2][0] = __builtin_amdgcn_mfma_f32_16x16x32_bf16(af, B[2][t], acc[2][0], 0, 0, 0);
            acc[3][0] = __builtin_amdgcn_mfma_f32_16x16x32_bf16(af, B[3][t], acc[3][0], 0, 0, 0);
        }
        #pragma unroll
        for (int rf = 0; rf < 4; ++rf) acc[rf][1] = BIASV;
        #pragma unroll
        for (int t = 0; t < 8; ++t) {
            bf16x8 af = *(const bf16x8*)((const char*)aoff[t] + bufb + 8192);
            acc[0][1] = __builtin_amdgcn_mfma_f32_16x16x32_bf16(af, B[0][t], acc[0][1], 0, 0, 0);
            acc[1][1] = __builtin_amdgcn_mfma_f32_16x16x32_bf16(af, B[1][t], acc[1][1], 0, 0, 0);
            acc[2][1] = __builtin_amdgcn_mfma_f32_16x16x32_bf16(af, B[2][t], acc[2][1], 0, 0, 0);
            acc[3][1] = __builtin_amdgcn_mfma_f32_16x16x32_bf16(af, B[3][t], acc[3][1], 0, 0, 0);
            {   // interleave: 2 cf0 scores of THIS chunk per t-step
                const int q0 = 2 * t, q1 = 2 * t + 1;
                const int rfA = q0 >> 2, rA = q0 & 3;
                const int rfB = q1 >> 2, rB = q1 & 3;
                unsigned bitsA = __float_as_uint(acc[rfA][0][rA]);
                unsigned uA = (bitsA & 0xFFFFFF00u) | (tb - (unsigned)rA);
                unsigned loA = umin(uA, U1[rfA]);
                U1[rfA] = umax(uA, U1[rfA]);
                U2[rfA] = umax(loA, U2[rfA]);
                unsigned bitsB = __float_as_uint(acc[rfB][0][rB]);
                unsigned uB = (bitsB & 0xFFFFFF00u) | (tb - (unsigned)rB);
                unsigned loB = umin(uB, U1[rfB]);
                U1[rfB] = umax(uB, U1[rfB]);
                U2[rfB] = umax(loB, U2[rfB]);
            }
        }
    };

    // 32 chunks, double-buffered (R1's proven schedule)
    stage(0, 0);
    __syncthreads();                  // drains B-loads + GLD(0)
    stage(1, 8192);
    compute(0, 255u);                 // chunk 0 (buf0)

    #pragma unroll 1
    for (int k = 0; k < 15; ++k) {
        const int c1 = 2 * k + 1;
        const unsigned tb = 255u - ((unsigned)c1 << 3);
        __syncthreads();
        stage(c1 + 1, 0);             // chunk 2k+2 -> buf0
        epi1(tb + 8u);                // cf1 of chunk 2k
        compute(16384, tb);           // chunk 2k+1 (buf1)
        __syncthreads();
        stage(c1 + 2, 8192);          // chunk 2k+3 -> buf1 (k=14 stages 31)
        epi1(tb);                     // cf1 of chunk 2k+1
        compute(0, tb - 8u);          // chunk 2k+2 (buf0)
    }
    __syncthreads();                  // drains GLD(31)
    epi1(255u - (30u << 3));
    compute(16384, 255u - (31u << 3));
    epi1(255u - (31u << 3));

    // decode to (key22<<10 | 1023-local), cross-qk merge top-4, store packed
    #pragma unroll
    for (int rf = 0; rf < 4; ++rf) {
        unsigned t1 = 255u - (U1[rf] & 255u);
        unsigned c1 = (t1 >> 3) * 32 + ((t1 >> 2) & 1) * 16 + qk * 4 + (t1 & 3);
        unsigned x1 = ((((U1[rf] & 0xFFFFFF00u) - 0x47000000u) >> 3) << 10) | (1023u - c1);
        unsigned t2 = 255u - (U2[rf] & 255u);
        unsigned c2 = (t2 >> 3) * 32 + ((t2 >> 2) & 1) * 16 + qk * 4 + (t2 & 3);
        unsigned x2 = ((((U2[rf] & 0xFFFFFF00u) - 0x47000000u) >> 3) << 10) | (1023u - c2);
        unsigned p1 = __shfl_xor(x1, 16);
        unsigned p2 = __shfl_xor(x2, 16);
        unsigned s1 = umax(x1, p1), tm = umin(x1, p1);
        unsigned ym = umax(x2, p2), s4 = umin(x2, p2);
        unsigned s2 = umax(tm, ym), s3 = umin(tm, ym);
        unsigned r1 = umax(s1, __shfl_xor(s4, 32));
        unsigned r2 = umax(s2, __shfl_xor(s3, 32));
        unsigned r3 = umax(s3, __shfl_xor(s2, 32));
        unsigned r4 = umax(s4, __shfl_xor(s1, 32));
        if (qk == 0) {
            int row = wv * 64 + rf * 16 + col;
            uint4v cw; cw.x = r1; cw.y = r2; cw.z = r3; cw.w = r4;
            *(uint4v*)(cand + ((size_t)slice * NROWS + n0 + row) * 4) = cw;
        }
    }
}

// --- 3: prune + zsq + COMPACTED 8-lane-coop fp64 re-score + loss + z_q -----
// 512 blocks x 256 threads; block = 32 rows x 32 candidates.
__global__ __launch_bounds__(256, 2)
void fixup_kernel(const float* __restrict__ z, const float* __restrict__ cb,
                  float* __restrict__ out, const unsigned* __restrict__ cand,
                  int fuse_zq) {
    __shared__ float zs[32 * 264];       // [row][c^((row>>2)<<2)], pad 8
    __shared__ double dp[8][32];         // zsq partials
    __shared__ float zsq_s[32];
    __shared__ unsigned qmx[32];
    __shared__ float dsc[32 * 33];       // [row][j]
    __shared__ unsigned cds[32 * 33];
    __shared__ unsigned wl[1024];        // worklist: row<<18 | j<<13 | code
    __shared__ unsigned wl_n;
    __shared__ unsigned bcode[32];
    __shared__ double lred[4];
    int tid = threadIdx.x;
    int n0 = blockIdx.x * 32;
    const float* zb = z + (size_t)(n0 >> 10) * (DIMC * HW) + (n0 & 1023);

    // stage z tile: thread = (row-quad q, channel cq); 128B segments
    {
        int q = tid & 7, cq = tid >> 3;
        #pragma unroll
        for (int i = 0; i < 8; ++i) {
            int c = cq + i * 32;
            float4 v = *(const float4*)(zb + (size_t)c * HW + q * 4);
            int sc = c ^ (q << 2);
            zs[(q * 4 + 0) * 264 + sc] = v.x;
            zs[(q * 4 + 1) * 264 + sc] = v.y;
            zs[(q * 4 + 2) * 264 + sc] = v.z;
            zs[(q * 4 + 3) * 264 + sc] = v.w;
        }
    }
    if (tid < 32) qmx[tid] = 0;
    if (tid == 0) wl_n = 0;

    // candidate words for all 4 row-batches (coalesced 128B segments)
    int j = tid >> 3, r = tid & 7;
    unsigned w[4];
    #pragma unroll
    for (int b = 0; b < 4; ++b)
        w[b] = cand[(((size_t)(j >> 2)) * NROWS + n0 + b * 8 + r) * 4 + (j & 3)];
    __syncthreads();

    // zsq from staged tile (f64, fixed order) + coarse row-max + dsc init
    {
        int row = tid & 31, cg = tid >> 5;
        const float* zrow = zs + row * 264;
        const int xr = (row >> 2) << 2;
        double s = 0.0;
        #pragma unroll
        for (int i = 0; i < 8; ++i) {
            int c = cg * 32 + i * 4;
            float4 zv = *(const float4*)(zrow + (c ^ xr));
            s += (double)zv.x * (double)zv.x + (double)zv.y * (double)zv.y
               + (double)zv.z * (double)zv.z + (double)zv.w * (double)zv.w;
        }
        dp[cg][row] = s;
    }
    #pragma unroll
    for (int b = 0; b < 4; ++b)
        atomicMax(&qmx[b * 8 + r], w[b] >> 10);
    for (int i = tid; i < 32 * 33; i += 256) { dsc[i] = FLT_MAX; cds[i] = 0xffffffffu; }
    __syncthreads();
    if (tid < 32) {
        double s = ((dp[0][tid] + dp[1][tid]) + (dp[2][tid] + dp[3][tid]))
                 + ((dp[4][tid] + dp[5][tid]) + (dp[6][tid] + dp[7][tid]));
        zsq_s[tid] = (float)s;
    }
    // build worklist of live candidates (order-independent processing)
    #pragma unroll
    for (int b = 0; b < 4; ++b) {
        int row = b * 8 + r;
        unsigned qv = w[b] >> 10;
        if (qv + PRUNE_T >= qmx[row]) {
            unsigned code = (unsigned)((j >> 2) * 1024) + 1023u - (w[b] & 1023u);
            unsigned e = ((unsigned)row << 18) | ((unsigned)j << 13) | code;
            unsigned pos = atomicAdd(&wl_n, 1u);
            wl[pos] = e;
        }
    }
    __syncthreads();

    // cooperative dots: 32 groups x 8 lanes; lane l: dims k*32 + l*4
    // (per-k: 8 lanes read 128B contiguous of cb row; z-LDS banks distinct)
    {
        int g = tid >> 3, l8 = tid & 7;
        int L = (int)wl_n;
        for (int base = 0; base < L; base += 32) {
            int idx = base + g;
            double part = 0.0;
            int row = 0, jj = 0;
            unsigned code = 0;
            if (idx < L) {
                unsigned e = wl[idx];
                row = (int)(e >> 18); jj = (int)((e >> 13) & 31u);
                code = e & 8191u;
                const float* eb = cb + (size_t)code * DIMC;
                const float* zrow = zs + row * 264;
                const int xr = (row >> 2) << 2;
                #pragma unroll
                for (int k = 0; k < 8; ++k) {
                    int c = k * 32 + l8 * 4;
                    float4 ev = *(const float4*)(eb + c);
                    float4 zv = *(const float4*)(zrow + (c ^ xr));
                    part += (double)zv.x * (double)ev.x + (double)zv.y * (double)ev.y
                          + (double)zv.z * (double)ev.z + (double)zv.w * (double)ev.w;
                }
            }
            part += __shfl_xor(part, 1);
            part += __shfl_xor(part, 2);
            part += __shfl_xor(part, 4);
            if (idx < L && l8 == 0) {
                dsc[row * 33 + jj] = fmaf(-2.0f, (float)part, zsq_s[row]);
                cds[row * 33 + jj] = code;
            }
        }
    }
    __syncthreads();
    if (tid < 32) {
        float bd = FLT_MAX; unsigned bi = 0xffffffffu;
        for (int jj = 0; jj < 32; ++jj) {
            float dv = dsc[tid * 33 + jj];
            unsigned k = cds[tid * 33 + jj];
            if (dv < bd || (dv == bd && k < bi)) { bd = dv; bi = k; }
        }
        out[IDX_OFF + n0 + tid] = (float)bi;
        bcode[tid] = bi;
    }
    __syncthreads();

    // fused loss on the staged tile: thread = (row, c-32-group), f64 partial
    {
        int row = tid & 31, cg = tid >> 5;
        const float* zrow = zs + row * 264;
        const int xr = (row >> 2) << 2;
        const float* e = cb + (size_t)bcode[row] * DIMC;
        double lacc = 0.0;
        #pragma unroll
        for (int i = 0; i < 8; ++i) {
            int c = cg * 32 + (((i + row) & 7) << 2);   // staggered quads
            float4 ev = *(const float4*)(e + c);
            float4 zv = *(const float4*)(zrow + (c ^ xr));
            double d0 = (double)ev.x - (double)zv.x;
            double d1 = (double)ev.y - (double)zv.y;
            double d2 = (double)ev.z - (double)zv.z;
            double d3 = (double)ev.w - (double)zv.w;
            lacc += d0 * d0 + d1 * d1 + d2 * d2 + d3 * d3;
        }
        #pragma unroll
        for (int off = 32; off; off >>= 1) lacc += __shfl_down(lacc, off);
        if ((tid & 63) == 0) lred[tid >> 6] = lacc;
    }
    __syncthreads();                 // all zs reads complete past this point
    if (tid == 0) {
        double part = (lred[0] + lred[1]) + (lred[2] + lred[3]);
        atomicAdd(out + LOSS_OFF, (float)(part * (1.25 / 4194304.0)));
    }

    if (fuse_zq) {
        // gather winner rows into zs (unswizzled [row][264])
        {
            int rr = tid >> 3, q = tid & 7;
            const float* e = cb + (size_t)bcode[rr] * DIMC;
            #pragma unroll
            for (int i = 0; i < 8; ++i) {
                int c = i * 32 + q * 4;
                *(float4*)(zs + rr * 264 + c) = *(const float4*)(e + c);
            }
        }
        __syncthreads();
        // scatter z_q: lane = (hw-quad 0-7, ch-group 0-31) -> 8x128B segs
        int hwq = tid & 7, ch0 = tid >> 3;
        int bb = n0 >> 10, hw0 = n0 & 1023;
        float* zqbase = out + (size_t)bb * (DIMC * HW) + hw0 + hwq * 4;
        #pragma unroll
        for (int i = 0; i < 8; ++i) {
            int c = ch0 + i * 32;
            float4 v;
            v.x = zs[(hwq * 4 + 0) * 264 + c];
            v.y = zs[(hwq * 4 + 1) * 264 + c];
            v.z = zs[(hwq * 4 + 2) * 264 + c];
            v.w = zs[(hwq * 4 + 3) * 264 + c];
            *(float4*)(zqbase + (size_t)c * HW) = v;
        }
    }
}

// --- 4 (fallback only): z_q gather->scatter, 1024 blocks x 256 thr ---------
__global__ __launch_bounds__(256)
void zq_kernel(const float* __restrict__ z, const float* __restrict__ cb,
               float* __restrict__ out) {
    __shared__ float lds[16 * 260];
    int tid = threadIdx.x;
    int n0 = blockIdx.x * 16;
    {
        int rr = tid >> 4, q = tid & 15;
        int code = (int)out[IDX_OFF + n0 + rr];
        const float* e = cb + (size_t)code * DIMC;
        #pragma unroll
        for (int jj = 0; jj < 4; ++jj) {
            int c = q * 4 + jj * 64;
            *(float4*)(lds + rr * 260 + c) = *(const float4*)(e + c);
        }
    }
    __syncthreads();
    int g = tid >> 2, rq = tid & 3;
    int b = n0 >> 10, hw0 = n0 & 1023;
    const size_t base = (size_t)b * (DIMC * HW) + hw0 + rq * 4;
    #pragma unroll
    for (int i = 0; i < 4; ++i) {
        int c = g + i * 64;
        float4 v;
        v.x = lds[(rq * 4 + 0) * 260 + c];
        v.y = lds[(rq * 4 + 1) * 260 + c];
        v.z = lds[(rq * 4 + 2) * 260 + c];
        v.w = lds[(rq * 4 + 3) * 260 + c];
        *(float4*)(out + base + (size_t)c * HW) = v;
    }
}

extern "C" void kernel_launch(void* const* d_in, const int* in_sizes, int n_in,
                              void* d_out, int out_size, void* d_ws, size_t ws_size,
                              hipStream_t stream) {
    const float* z  = (const float*)d_in[0];
    const float* cb = (const float*)d_in[1];
    float* out = (float*)d_out;

    const bool fuse = (d_ws != nullptr) && (ws_size >= CAND_BYTES);
    unsigned* candp = fuse ? (unsigned*)d_ws : (unsigned*)(out + CAND_OFF);

    prep_kernel<<<2048, 256, 0, stream>>>(z, cb, out);
    argmin_kernel<<<dim3(64, NSLICE), 256, 0, stream>>>(out, candp);
    fixup_kernel<<<512, 256, 0, stream>>>(z, cb, out, candp, fuse ? 1 : 0);
    if (!fuse)
        zq_kernel<<<1024, 256, 0, stream>>>(z, cb, out);
}

// Round 13
// 156.242 us; speedup vs baseline: 1.3127x; 1.0019x over previous
//
#include <hip/hip_runtime.h>
#include <cfloat>

// ---------------------------------------------------------------------------
// VectorQuantizer: z (16,256,32,32) f32, codebook (8192,256) f32
// outputs (f32 concat): z_q [4194304], loss [1], idx-as-float [16384]
// Validated semantics (R2-R6): idx = argmin_k fl32(zsq - 2*dot32(z,e_k)),
// lowest-index tie-break; bf16-MFMA coarse top-4 x 8 slices -> 32 cands/row;
// prune to coarse margin of row max; survivors re-scored fp64->fp32.
// ARGMIN FROZEN at ~70us, 8 waves/CU saturation (R8/R9/R13/R14 nulls).
// R18 (156.5us): fixup worklist compaction + 8-lane coop dots (48.8 -> ~35).
// R19: fixup v4 — same math, 2x wave parallelism: 512 threads/block
//   (2 blocks/CU x 8 waves = 16 waves/CU, was 8); every barrier phase's
//   latency halves. LDS pitch 264 -> 266 so the z_q scatter's LDS column
//   reads are 2-way (free, was 8-way); stage/dot patterns stay conflict-free
//   (derived). Dot summation order byte-identical to R18's passed config.
// R20: byte-identical resubmit of R19 (3rd infra flake, rounds 4/8/12
//   periodicity; coverage/race/LDS/occupancy audits all clean).
// ---------------------------------------------------------------------------

#define NROWS 16384
#define NCODE 8192
#define DIMC  256
#define HW    1024
#define ZQN   4194304

// scratch inside d_out's z_q region (dead before z_q is written):
#define ZT_OFF   0         // bf16 z*2^21 [16384][256] as ushort = 2097152 floats
#define CBT_OFF  2097152   // bf16 codebook [8192][256]          = 1048576 floats
#define CAND_OFF 3145728   // fallback cand: 8*16384*4 uints -> ends 3670016
#define LOSS_OFF ZQN
#define IDX_OFF  (ZQN + 1)

#define NSLICE 8
#define CAND_BYTES ((size_t)NSLICE * NROWS * 4 * sizeof(unsigned))   // 2 MB
#define PRUNE_T 4300u      // key units (8 float-ulps each, worst 1.49e-8 dot):
                           // covers d-bin 3.05e-5 + 2x6sigma bf16 + tag-quant
#define ZSCALE 2097152.0f  // 2^21, exact in bf16/f32
#define ZP 266             // fixup LDS row pitch (scatter banks 2-way free)

typedef __attribute__((ext_vector_type(8))) short bf16x8;
typedef __attribute__((ext_vector_type(4))) float f32x4;
typedef __attribute__((ext_vector_type(4))) unsigned int uint4v;

__device__ __forceinline__ unsigned umax(unsigned a, unsigned b) { return a > b ? a : b; }
__device__ __forceinline__ unsigned umin(unsigned a, unsigned b) { return a < b ? a : b; }

__device__ __forceinline__ unsigned short f2bf(float f) {   // RNE
    unsigned u = __float_as_uint(f);
    return (unsigned short)((u + 0x7fffu + ((u >> 16) & 1u)) >> 16);
}

#define GLD_LDS16(gptr, lptr) \
  __builtin_amdgcn_global_load_lds((const __attribute__((address_space(1))) unsigned int*)(const void*)(gptr), \
                                   (__attribute__((address_space(3))) unsigned int*)(lptr), 16, 0, 0)

// --- 1: fused prep: zt transpose+cvt(*2^21) | cbt cvt | loss zero ----------
__global__ void prep_kernel(const float* __restrict__ z, const float* __restrict__ cb,
                            float* __restrict__ out) {
    int bid = blockIdx.x;
    int tid = threadIdx.x;
    if (bid < 1024) {
        __shared__ unsigned short lds[64 * 65];
        unsigned short* zt = (unsigned short*)(out + ZT_OFF);
        int c0 = (bid & 3) * 64;
        int n0 = (bid >> 2) * 64;
        const float* zb = z + (size_t)(n0 >> 10) * (DIMC * HW) + (n0 & 1023);
        #pragma unroll
        for (int i = 0; i < 4; ++i) {
            int f = tid + i * 256;
            int cl = f >> 4, n4 = f & 15;
            float4 v = *(const float4*)(zb + (size_t)(c0 + cl) * HW + n4 * 4);
            lds[(n4 * 4 + 0) * 65 + cl] = f2bf(v.x * ZSCALE);
            lds[(n4 * 4 + 1) * 65 + cl] = f2bf(v.y * ZSCALE);
            lds[(n4 * 4 + 2) * 65 + cl] = f2bf(v.z * ZSCALE);
            lds[(n4 * 4 + 3) * 65 + cl] = f2bf(v.w * ZSCALE);
        }
        __syncthreads();
        #pragma unroll
        for (int i = 0; i < 2; ++i) {
            int f = tid + i * 256;
            int nl = f >> 3, oct = f & 7;
            const unsigned short* p = lds + nl * 65 + oct * 8;
            uint4v u;
            u.x = (unsigned)p[0] | ((unsigned)p[1] << 16);
            u.y = (unsigned)p[2] | ((unsigned)p[3] << 16);
            u.z = (unsigned)p[4] | ((unsigned)p[5] << 16);
            u.w = (unsigned)p[6] | ((unsigned)p[7] << 16);
            *(uint4v*)(zt + (size_t)(n0 + nl) * DIMC + c0 + oct * 8) = u;
        }
    } else {
        unsigned short* cbt = (unsigned short*)(out + CBT_OFF);
        size_t t = (size_t)(bid - 1024) * 256 + tid;
        float4 a = *(const float4*)(cb + t * 8);
        float4 b = *(const float4*)(cb + t * 8 + 4);
        uint4v u;
        u.x = (unsigned)f2bf(a.x) | ((unsigned)f2bf(a.y) << 16);
        u.y = (unsigned)f2bf(a.z) | ((unsigned)f2bf(a.w) << 16);
        u.z = (unsigned)f2bf(b.x) | ((unsigned)f2bf(b.y) << 16);
        u.w = (unsigned)f2bf(b.z) | ((unsigned)f2bf(b.w) << 16);
        *(uint4v*)(cbt + t * 8) = u;
        if (bid == 1024 && tid == 0) out[LOSS_OFF] = 0.0f;
    }
}

// --- 2: bf16 MFMA argmin (R1's proven 69.5us form) -------------------------
// grid (64 row-blocks, 8 slices), 256 threads. Block: 256 rows x 1024 codes.
__global__ __launch_bounds__(256, 2)
void argmin_kernel(const float* __restrict__ out, unsigned* __restrict__ cand) {
    __shared__ __align__(16) unsigned short a_s[2 * 32 * 256];   // 32 KB dbuf
    const unsigned short* zt  = (const unsigned short*)(out + ZT_OFF);
    const unsigned short* cbt = (const unsigned short*)(out + CBT_OFF);

    int tid = threadIdx.x;
    int lane = tid & 63;
    int wv = tid >> 6;
    int col = lane & 15, qk = lane >> 4;
    int n0 = blockIdx.x * 256;
    int slice = blockIdx.y;

    bf16x8 B[4][8];
    #pragma unroll
    for (int rf = 0; rf < 4; ++rf)
        #pragma unroll
        for (int t = 0; t < 8; ++t)
            B[rf][t] = *(const bf16x8*)(zt + (size_t)(n0 + wv * 64 + rf * 16 + col) * DIMC
                                           + t * 32 + qk * 8);

    int rl2 = lane >> 5;
    int jsl = lane & 31;
    const unsigned short* srcb[4];
    #pragma unroll
    for (int c = 0; c < 4; ++c) {
        int rloc = (wv * 4 + c) * 2 + rl2;
        int src16 = jsl ^ (rloc & 7) ^ ((rloc & 8) >> 1);
        srcb[c] = cbt + ((size_t)slice * 1024 + rloc) * DIMC + src16 * 8;
    }

    unsigned U1[4] = {0, 0, 0, 0}, U2[4] = {0, 0, 0, 0};

    const unsigned sb = (unsigned)((col & 7) ^ ((col & 8) >> 1));
    const unsigned short* aoff[8];
    #pragma unroll
    for (int t = 0; t < 8; ++t)
        aoff[t] = a_s + col * 256 + (((unsigned)(qk + 4 * t)) ^ sb) * 8;

    f32x4 acc[4][2];
    const f32x4 BIASV = (f32x4){131072.0f, 131072.0f, 131072.0f, 131072.0f};

    auto stage = [&](int ch, int dsto /*shorts*/) {
        const size_t off = (size_t)ch * 32 * DIMC;
        unsigned short* dst = a_s + dsto;
        #pragma unroll
        for (int c = 0; c < 4; ++c)
            GLD_LDS16(srcb[c] + off, dst + (wv * 4 + c) * 512);
    };

    auto epi1 = [&](unsigned tb) {
        #pragma unroll
        for (int rf = 0; rf < 4; ++rf)
            #pragma unroll
            for (int r = 0; r < 4; ++r) {
                unsigned bits = __float_as_uint(acc[rf][1][r]);
                unsigned u = (bits & 0xFFFFFF00u) | (tb - (unsigned)(4 + r));
                unsigned lo = umin(u, U1[rf]);
                U1[rf] = umax(u, U1[rf]);
                U2[rf] = umax(lo, U2[rf]);
            }
    };

    auto compute = [&](int bufb /*bytes*/, unsigned tb) {
        #pragma unroll
        for (int rf = 0; rf < 4; ++rf) acc[rf][0] = BIASV;
        #pragma unroll
        for (int t = 0; t < 8; ++t) {
            bf16x8 af = *(const bf16x8*)((const char*)aoff[t] + bufb);
            acc[0][0] = __builtin_amdgcn_mfma_f32_16x16x32_bf16(af, B[0][t], acc[0][0], 0, 0, 0);
            acc[1][0] = __builtin_amdgcn_mfma_f32_16x16x32_bf16(af, B[1][t], acc[1][0], 0, 0, 0);
            acc[2][0] = __builtin_amdgcn_mfma_f32_16x16x32_bf16(af, B[2][t], acc[2][0], 0, 0, 0);
            acc[3][0] = __builtin_amdgcn_mfma_f32_16x16x32_bf16(af, B[3][t], acc[3][0], 0, 0, 0);
        }
        #pragma unroll
        for (int rf = 0; rf < 4; ++rf) acc[rf][1] = BIASV;
        #pragma unroll
        for (int t = 0; t < 8; ++t) {
            bf16x8 af = *(const bf16x8*)((const char*)aoff[t] + bufb + 8192);
            acc[0][1] = __builtin_amdgcn_mfma_f32_16x16x32_bf16(af, B[0][t], acc[0][1], 0, 0, 0);
            acc[1][1] = __builtin_amdgcn_mfma_f32_16x16x32_bf16(af, B[1][t], acc[1][1], 0, 0, 0);
            acc[2][1] = __builtin_amdgcn_mfma_f32_16x16x32_bf16(af, B[2][t], acc[2][1], 0, 0, 0);
            acc[3][1] = __builtin_amdgcn_mfma_f32_16x16x32_bf16(af, B[3][t], acc[3][1], 0, 0, 0);
            {   // interleave: 2 cf0 scores of THIS chunk per t-step
                const int q0 = 2 * t, q1 = 2 * t + 1;
                const int rfA = q0 >> 2, rA = q0 & 3;
                const int rfB = q1 >> 2, rB = q1 & 3;
                unsigned bitsA = __float_as_uint(acc[rfA][0][rA]);
                unsigned uA = (bitsA & 0xFFFFFF00u) | (tb - (unsigned)rA);
                unsigned loA = umin(uA, U1[rfA]);
                U1[rfA] = umax(uA, U1[rfA]);
                U2[rfA] = umax(loA, U2[rfA]);
                unsigned bitsB = __float_as_uint(acc[rfB][0][rB]);
                unsigned uB = (bitsB & 0xFFFFFF00u) | (tb - (unsigned)rB);
                unsigned loB = umin(uB, U1[rfB]);
                U1[rfB] = umax(uB, U1[rfB]);
                U2[rfB] = umax(loB, U2[rfB]);
            }
        }
    };

    // 32 chunks, double-buffered (R1's proven schedule)
    stage(0, 0);
    __syncthreads();                  // drains B-loads + GLD(0)
    stage(1, 8192);
    compute(0, 255u);                 // chunk 0 (buf0)

    #pragma unroll 1
    for (int k = 0; k < 15; ++k) {
        const int c1 = 2 * k + 1;
        const unsigned tb = 255u - ((unsigned)c1 << 3);
        __syncthreads();
        stage(c1 + 1, 0);             // chunk 2k+2 -> buf0
        epi1(tb + 8u);                // cf1 of chunk 2k
        compute(16384, tb);           // chunk 2k+1 (buf1)
        __syncthreads();
        stage(c1 + 2, 8192);          // chunk 2k+3 -> buf1 (k=14 stages 31)
        epi1(tb);                     // cf1 of chunk 2k+1
        compute(0, tb - 8u);          // chunk 2k+2 (buf0)
    }
    __syncthreads();                  // drains GLD(31)
    epi1(255u - (30u << 3));
    compute(16384, 255u - (31u << 3));
    epi1(255u - (31u << 3));

    // decode to (key22<<10 | 1023-local), cross-qk merge top-4, store packed
    #pragma unroll
    for (int rf = 0; rf < 4; ++rf) {
        unsigned t1 = 255u - (U1[rf] & 255u);
        unsigned c1 = (t1 >> 3) * 32 + ((t1 >> 2) & 1) * 16 + qk * 4 + (t1 & 3);
        unsigned x1 = ((((U1[rf] & 0xFFFFFF00u) - 0x47000000u) >> 3) << 10) | (1023u - c1);
        unsigned t2 = 255u - (U2[rf] & 255u);
        unsigned c2 = (t2 >> 3) * 32 + ((t2 >> 2) & 1) * 16 + qk * 4 + (t2 & 3);
        unsigned x2 = ((((U2[rf] & 0xFFFFFF00u) - 0x47000000u) >> 3) << 10) | (1023u - c2);
        unsigned p1 = __shfl_xor(x1, 16);
        unsigned p2 = __shfl_xor(x2, 16);
        unsigned s1 = umax(x1, p1), tm = umin(x1, p1);
        unsigned ym = umax(x2, p2), s4 = umin(x2, p2);
        unsigned s2 = umax(tm, ym), s3 = umin(tm, ym);
        unsigned r1 = umax(s1, __shfl_xor(s4, 32));
        unsigned r2 = umax(s2, __shfl_xor(s3, 32));
        unsigned r3 = umax(s3, __shfl_xor(s2, 32));
        unsigned r4 = umax(s4, __shfl_xor(s1, 32));
        if (qk == 0) {
            int row = wv * 64 + rf * 16 + col;
            uint4v cw; cw.x = r1; cw.y = r2; cw.z = r3; cw.w = r4;
            *(uint4v*)(cand + ((size_t)slice * NROWS + n0 + row) * 4) = cw;
        }
    }
}

// --- 3: fixup v4: 512 threads (16 waves/CU), worklist + coop dots ----------
// 512 blocks x 512 threads; block = 32 rows x 32 candidates.
__global__ __launch_bounds__(512, 2)
void fixup_kernel(const float* __restrict__ z, const float* __restrict__ cb,
                  float* __restrict__ out, const unsigned* __restrict__ cand,
                  int fuse_zq) {
    __shared__ float zs[32 * ZP];        // [row][c^((row>>2)<<2)], pitch 266
    __shared__ double dp[16][32];        // zsq partials
    __shared__ float zsq_s[32];
    __shared__ unsigned qmx[32];
    __shared__ float dsc[32 * 33];       // [row][j]
    __shared__ unsigned cds[32 * 33];
    __shared__ unsigned wl[1024];        // worklist: row<<18 | j<<13 | code
    __shared__ unsigned wl_n;
    __shared__ unsigned bcode[32];
    __shared__ double lred[8];
    int tid = threadIdx.x;
    int n0 = blockIdx.x * 32;
    const float* zb = z + (size_t)(n0 >> 10) * (DIMC * HW) + (n0 & 1023);

    // stage z tile: thread = (row-quad q 0-7, channel cq 0-63); 128B segments
    {
        int q = tid & 7, cq = tid >> 3;
        #pragma unroll
        for (int i = 0; i < 4; ++i) {
            int c = cq + i * 64;
            float4 v = *(const float4*)(zb + (size_t)c * HW + q * 4);
            int sc = c ^ (q << 2);
            zs[(q * 4 + 0) * ZP + sc] = v.x;
            zs[(q * 4 + 1) * ZP + sc] = v.y;
            zs[(q * 4 + 2) * ZP + sc] = v.z;
            zs[(q * 4 + 3) * ZP + sc] = v.w;
        }
    }
    if (tid < 32) qmx[tid] = 0;
    if (tid == 0) wl_n = 0;

    // candidate words: thread = (j 0-31, r16 0-15), 2 row-batches; 256B segs
    int j = tid >> 4, r16 = tid & 15;
    unsigned w[2];
    #pragma unroll
    for (int b = 0; b < 2; ++b)
        w[b] = cand[(((size_t)(j >> 2)) * NROWS + n0 + b * 16 + r16) * 4 + (j & 3)];
    __syncthreads();

    // zsq partials (f64, fixed order) + coarse row-max + dsc init
    {
        int row = tid & 31, cg = tid >> 5;   // cg 0-15, 16 dims each
        const float* zrow = zs + row * ZP;
        const int xr = (row >> 2) << 2;
        double s = 0.0;
        #pragma unroll
        for (int i = 0; i < 4; ++i) {
            int c = cg * 16 + i * 4;
            float4 zv = *(const float4*)(zrow + (c ^ xr));
            s += (double)zv.x * (double)zv.x + (double)zv.y * (double)zv.y
               + (double)zv.z * (double)zv.z + (double)zv.w * (double)zv.w;
        }
        dp[cg][row] = s;
    }
    #pragma unroll
    for (int b = 0; b < 2; ++b)
        atomicMax(&qmx[b * 16 + r16], w[b] >> 10);
    for (int i = tid; i < 32 * 33; i += 512) { dsc[i] = FLT_MAX; cds[i] = 0xffffffffu; }
    __syncthreads();
    if (tid < 32) {
        double s = (((dp[0][tid] + dp[1][tid]) + (dp[2][tid] + dp[3][tid]))
                 +  ((dp[4][tid] + dp[5][tid]) + (dp[6][tid] + dp[7][tid])))
                 + (((dp[8][tid] + dp[9][tid]) + (dp[10][tid] + dp[11][tid]))
                 +  ((dp[12][tid] + dp[13][tid]) + (dp[14][tid] + dp[15][tid])));
        zsq_s[tid] = (float)s;
    }
    // build worklist of live candidates (order-independent processing)
    #pragma unroll
    for (int b = 0; b < 2; ++b) {
        int row = b * 16 + r16;
        unsigned qv = w[b] >> 10;
        if (qv + PRUNE_T >= qmx[row]) {
            unsigned code = (unsigned)((j >> 2) * 1024) + 1023u - (w[b] & 1023u);
            unsigned e = ((unsigned)row << 18) | ((unsigned)j << 13) | code;
            unsigned pos = atomicAdd(&wl_n, 1u);
            wl[pos] = e;
        }
    }
    __syncthreads();

    // cooperative dots: 64 groups x 8 lanes; lane l: dims k*32 + l*4
    // (same summation order as R18's validated config)
    {
        int g = tid >> 3, l8 = tid & 7;
        int L = (int)wl_n;
        for (int base = 0; base < L; base += 64) {
            int idx = base + g;
            double part = 0.0;
            int row = 0, jj = 0;
            unsigned code = 0;
            if (idx < L) {
                unsigned e = wl[idx];
                row = (int)(e >> 18); jj = (int)((e >> 13) & 31u);
                code = e & 8191u;
                const float* eb = cb + (size_t)code * DIMC;
                const float* zrow = zs + row * ZP;
                const int xr = (row >> 2) << 2;
                #pragma unroll
                for (int k = 0; k < 8; ++k) {
                    int c = k * 32 + l8 * 4;
                    float4 ev = *(const float4*)(eb + c);
                    float4 zv = *(const float4*)(zrow + (c ^ xr));
                    part += (double)zv.x * (double)ev.x + (double)zv.y * (double)ev.y
                          + (double)zv.z * (double)ev.z + (double)zv.w * (double)ev.w;
                }
            }
            part += __shfl_xor(part, 1);
            part += __shfl_xor(part, 2);
            part += __shfl_xor(part, 4);
            if (idx < L && l8 == 0) {
                dsc[row * 33 + jj] = fmaf(-2.0f, (float)part, zsq_s[row]);
                cds[row * 33 + jj] = code;
            }
        }
    }
    __syncthreads();
    if (tid < 32) {
        float bd = FLT_MAX; unsigned bi = 0xffffffffu;
        for (int jj = 0; jj < 32; ++jj) {
            float dv = dsc[tid * 33 + jj];
            unsigned k = cds[tid * 33 + jj];
            if (dv < bd || (dv == bd && k < bi)) { bd = dv; bi = k; }
        }
        out[IDX_OFF + n0 + tid] = (float)bi;
        bcode[tid] = bi;
    }
    __syncthreads();

    // fused loss: thread = (row 0-31, cg 0-15), 16 dims staggered; f64
    {
        int row = tid & 31, cg = tid >> 5;
        const float* zrow = zs + row * ZP;
        const int xr = (row >> 2) << 2;
        const float* e = cb + (size_t)bcode[row] * DIMC;
        double lacc = 0.0;
        #pragma unroll
        for (int i = 0; i < 4; ++i) {
            int c = cg * 16 + (((i + row) & 3) << 2);   // staggered quads
            float4 ev = *(const float4*)(e + c);
            float4 zv = *(const float4*)(zrow + (c ^ xr));
            double d0 = (double)ev.x - (double)zv.x;
            double d1 = (double)ev.y - (double)zv.y;
            double d2 = (double)ev.z - (double)zv.z;
            double d3 = (double)ev.w - (double)zv.w;
            lacc += d0 * d0 + d1 * d1 + d2 * d2 + d3 * d3;
        }
        #pragma unroll
        for (int off = 32; off; off >>= 1) lacc += __shfl_down(lacc, off);
        if ((tid & 63) == 0) lred[tid >> 6] = lacc;
    }
    __syncthreads();                 // all zs reads complete past this point
    if (tid == 0) {
        double part = ((lred[0] + lred[1]) + (lred[2] + lred[3]))
                    + ((lred[4] + lred[5]) + (lred[6] + lred[7]));
        atomicAdd(out + LOSS_OFF, (float)(part * (1.25 / 4194304.0)));
    }

    if (fuse_zq) {
        // gather winner rows into zs (unswizzled, pitch ZP)
        {
            int rr = tid >> 4, q = tid & 15;
            const float* e = cb + (size_t)bcode[rr] * DIMC;
            #pragma unroll
            for (int i = 0; i < 4; ++i) {
                int c = q * 4 + i * 64;
                *(float4*)(zs + rr * ZP + c) = *(const float4*)(e + c);
            }
        }
        __syncthreads();
        // scatter z_q: lane = (hwq 0-7, ch0 0-63) -> 128B segs per channel;
        // LDS column reads 2-way (pitch 266)
        int hwq = tid & 7, ch0 = tid >> 3;
        int bb = n0 >> 10, hw0 = n0 & 1023;
        float* zqbase = out + (size_t)bb * (DIMC * HW) + hw0 + hwq * 4;
        #pragma unroll
        for (int i = 0; i < 4; ++i) {
            int c = ch0 + i * 64;
            float4 v;
            v.x = zs[(hwq * 4 + 0) * ZP + c];
            v.y = zs[(hwq * 4 + 1) * ZP + c];
            v.z = zs[(hwq * 4 + 2) * ZP + c];
            v.w = zs[(hwq * 4 + 3) * ZP + c];
            *(float4*)(zqbase + (size_t)c * HW) = v;
        }
    }
}

// --- 4 (fallback only): z_q gather->scatter, 1024 blocks x 256 thr ---------
__global__ __launch_bounds__(256)
void zq_kernel(const float* __restrict__ z, const float* __restrict__ cb,
               float* __restrict__ out) {
    __shared__ float lds[16 * 260];
    int tid = threadIdx.x;
    int n0 = blockIdx.x * 16;
    {
        int rr = tid >> 4, q = tid & 15;
        int code = (int)out[IDX_OFF + n0 + rr];
        const float* e = cb + (size_t)code * DIMC;
        #pragma unroll
        for (int jj = 0; jj < 4; ++jj) {
            int c = q * 4 + jj * 64;
            *(float4*)(lds + rr * 260 + c) = *(const float4*)(e + c);
        }
    }
    __syncthreads();
    int g = tid >> 2, rq = tid & 3;
    int b = n0 >> 10, hw0 = n0 & 1023;
    const size_t base = (size_t)b * (DIMC * HW) + hw0 + rq * 4;
    #pragma unroll
    for (int i = 0; i < 4; ++i) {
        int c = g + i * 64;
        float4 v;
        v.x = lds[(rq * 4 + 0) * 260 + c];
        v.y = lds[(rq * 4 + 1) * 260 + c];
        v.z = lds[(rq * 4 + 2) * 260 + c];
        v.w = lds[(rq * 4 + 3) * 260 + c];
        *(float4*)(out + base + (size_t)c * HW) = v;
    }
}

extern "C" void kernel_launch(void* const* d_in, const int* in_sizes, int n_in,
                              void* d_out, int out_size, void* d_ws, size_t ws_size,
                              hipStream_t stream) {
    const float* z  = (const float*)d_in[0];
    const float* cb = (const float*)d_in[1];
    float* out = (float*)d_out;

    const bool fuse = (d_ws != nullptr) && (ws_size >= CAND_BYTES);
    unsigned* candp = fuse ? (unsigned*)d_ws : (unsigned*)(out + CAND_OFF);

    prep_kernel<<<2048, 256, 0, stream>>>(z, cb, out);
    argmin_kernel<<<dim3(64, NSLICE), 256, 0, stream>>>(out, candp);
    fixup_kernel<<<512, 512, 0, stream>>>(z, cb, out, candp, fuse ? 1 : 0);
    if (!fuse)
        zq_kernel<<<1024, 256, 0, stream>>>(z, cb, out);
}